// Round 12
// baseline (399.670 us; speedup 1.0000x reference)
//
#include <hip/hip_runtime.h>
#include <hip/hip_bf16.h>
#include <stdint.h>

// Problem constants (B=8, S=8192, K=1024, N=1024, G=128)
#define M_DIM 65536
#define K_DIM 1024
#define N_DIM 1024
#define NGRP  8

// 128x128 i8 GEMM, BK=64, static dbuf (r9 skeleton) + fused input quant
#define T_BM 128
#define T_BN 128
#define T_BK 64
#define T_NKT (K_DIM / T_BK)    // 16

typedef float f32x4 __attribute__((ext_vector_type(4)));
typedef int   ix4   __attribute__((ext_vector_type(4)));

// ---------------- prep: wd = w_q - w_zp (int8) [N][K], bias -> f32 ----------------
__global__ void prep_wd_kernel(const int* __restrict__ w_q,
                               const int* __restrict__ w_zp,
                               const int* __restrict__ bias_q,
                               const float* __restrict__ bias_scale,
                               int8_t* __restrict__ Wd,
                               float* __restrict__ bias_f) {
    const int n = blockIdx.x;       // 0..1023
    const int t = threadIdx.x;      // 0..255
    const int k0 = t * 4;
    const int g = k0 >> 7;
    const int zp = w_zp[n * NGRP + g];
    const int4 wq = *reinterpret_cast<const int4*>(w_q + (size_t)n * K_DIM + k0);
    union { int u; int8_t b[4]; } pk;
    pk.b[0] = (int8_t)(wq.x - zp);
    pk.b[1] = (int8_t)(wq.y - zp);
    pk.b[2] = (int8_t)(wq.z - zp);
    pk.b[3] = (int8_t)(wq.w - zp);
    *reinterpret_cast<int*>(Wd + (size_t)n * K_DIM + k0) = pk.u;
    if (t == 0) bias_f[n] = ((float)bias_q[n] - 128.0f) * bias_scale[n];
}

// ---------------- fused 128x128 i8 GEMM (r9 skeleton + in-kernel A-quant) ----------------
// 256 thr = 4 waves (2x2), wave owns 64x64. Static dbuf, plain __syncthreads
// (proven fastest structure, r9: 154us). Per K-64 tile:
//   1. issue 8 f32x4 A-loads for tile kt+1 (T14 issue-early)
//   2. issue B gload_lds for kt+1 (pre-swizzled source)
//   3. ds_read frags of kt | 16 MFMA C=0 | per-tile CVT facc += ws*S  (r9 verbatim)
//   4. quant A-regs -> 2 x ds_write_b128 into swizzled slots (T14 write-late;
//      f32 load latency hidden under step 3)
//   5. __syncthreads (drains lgkm: A-writes visible; vmcnt: B DMA done; WAR ok)
// Exactness: S_t = i32 dot (K=64), facc = sum_t ws_g*S_t in f32 (r9 math).
// in_s folded into WS; in_zp folded into clamp bounds.
__global__ __launch_bounds__(256) void gemm128_i8f_kernel(
    const float* __restrict__ x,
    const int8_t* __restrict__ Wd,
    const float* __restrict__ w_scale,
    const float* __restrict__ bias_f,
    const float* __restrict__ in_scale_p, const int* __restrict__ in_zp_p,
    const float* __restrict__ out_scale_p, const int* __restrict__ out_zp_p,
    float* __restrict__ out)
{
    __shared__ __align__(16) int8_t Abuf[2][T_BM * T_BK];   // 2 x 8 KB
    __shared__ __align__(16) int8_t Bbuf[2][T_BN * T_BK];   // 2 x 8 KB
    __shared__ float WS[NGRP * T_BN];                        // 4 KB [g][n_local]

    const int t = threadIdx.x;
    // bijective XCD swizzle: grid=4096, 8 XCDs, 512 blocks/XCD;
    // consecutive local bids share the A (x) panel -> L2/L3 absorbs 8x reuse.
    const int bid = (blockIdx.x & 7) * 512 + (blockIdx.x >> 3);
    const int nt = bid & 7;
    const int mt = bid >> 3;
    const int m0 = mt * T_BM;
    const int n0 = nt * T_BN;

    const int wid = t >> 6;
    const int lane = t & 63;
    const int wr = wid >> 1, wc = wid & 1;     // 2x2 waves, each owns 64x64
    const int lrow = lane & 15;
    const int kslot = lane >> 4;               // 16B k-chunk within 64B row
    const int koff = ((kslot ^ ((lrow >> 1) & 3)) << 4);   // XOR swizzle (r2-r11)
    const int widoff = wid * 1024;

    const int8_t* Bbase = Wd + (size_t)n0 * K_DIM;

    const float in_s = in_scale_p[0];
    const float inv = 1.0f / in_s;
    const float izp = (float)in_zp_p[0];
    const float qlo = -128.0f - izp;           // clip(r+zp,-128,127)-zp == clamp(r,lo,hi)
    const float qhi = 127.0f - izp;

    // ---- preload w_scale panel [g][n_local], folded with in_s ----
    {
        const int nl = t >> 1;                 // 0..127
        const int g4 = (t & 1) * 4;
        const float4 wv = *reinterpret_cast<const float4*>(
            w_scale + (size_t)(n0 + nl) * NGRP + g4);
        WS[(g4 + 0) * T_BN + nl] = wv.x * in_s;
        WS[(g4 + 1) * T_BN + nl] = wv.y * in_s;
        WS[(g4 + 2) * T_BN + nl] = wv.z * in_s;
        WS[(g4 + 3) * T_BN + nl] = wv.w * in_s;
    }

    // ---- A reg-staging: thread t owns chunks {t, 256+t}; chunk c covers
    // logical k-slot sl=(c&3)^((r>>1)&3) of row r=c>>2, written to phys slot c&3.
    float4 areg[2][4];                          // 32 f32 in flight
    auto loadA = [&](int kt) {
        const int k0 = kt * T_BK;
#pragma unroll
        for (int j = 0; j < 2; ++j) {
            const int c = j * 256 + t;
            const int r = c >> 2;
            const int sl = (c & 3) ^ ((r >> 1) & 3);
            const float* src = x + (size_t)(m0 + r) * K_DIM + k0 + sl * 16;
#pragma unroll
            for (int q = 0; q < 4; ++q)
                areg[j][q] = *reinterpret_cast<const float4*>(src + q * 4);
        }
    };
    auto writeA = [&](int8_t* dst) {
#pragma unroll
        for (int j = 0; j < 2; ++j) {
            const int c = j * 256 + t;
            const int r = c >> 2;
            const int phys = c & 3;
            union { int4 u; int8_t b[16]; } pk;
#pragma unroll
            for (int q = 0; q < 4; ++q) {
                const float4 v = areg[j][q];
                const float vv[4] = {v.x, v.y, v.z, v.w};
#pragma unroll
                for (int e = 0; e < 4; ++e) {
                    float qq = rintf(vv[e] * inv);           // RNE = jnp.round
                    qq = fminf(fmaxf(qq, qlo), qhi);         // zp-folded clamp
                    pk.b[q * 4 + e] = (int8_t)qq;
                }
            }
            *reinterpret_cast<int4*>(dst + r * 64 + phys * 16) = pk.u;
        }
    };

    // B staging via global_load_lds, pre-swizzled source (0-conflict, r2-r11)
    auto stageB = [&](int8_t* dst, int kt) {
        const int k0 = kt * T_BK;
#pragma unroll
        for (int j = 0; j < 2; ++j) {
            const int c = j * 256 + t;
            const int r = c >> 2;
            const int sl = (c & 3) ^ ((r >> 1) & 3);
            const int8_t* src = Bbase + (size_t)r * K_DIM + k0 + sl * 16;
            __builtin_amdgcn_global_load_lds(
                (const __attribute__((address_space(1))) void*)src,
                (__attribute__((address_space(3))) void*)(dst + j * 4096 + widoff),
                16, 0, 0);
        }
    };

    f32x4 facc[4][4];
#pragma unroll
    for (int mi = 0; mi < 4; ++mi)
#pragma unroll
        for (int ni = 0; ni < 4; ++ni)
            facc[mi][ni] = (f32x4){0.f, 0.f, 0.f, 0.f};

    // prologue: tile 0 into buf0 (A reg->quant->LDS, B DMA); barrier drains all
    loadA(0);
    stageB(&Bbuf[0][0], 0);
    writeA(&Abuf[0][0]);
    __syncthreads();

#pragma unroll 1
    for (int kt = 0; kt < T_NKT; ++kt) {
        const int buf = kt & 1;
        const bool more = (kt + 1 < T_NKT);
        if (more) {
            loadA(kt + 1);                      // issue-early: latency under MFMA
            stageB(&Bbuf[buf ^ 1][0], kt + 1);
        }

        ix4 af[4], bfr[4];
#pragma unroll
        for (int i = 0; i < 4; ++i) {
            const int arow = wr * 64 + i * 16 + lrow;
            af[i] = *reinterpret_cast<const ix4*>(&Abuf[buf][arow * 64 + koff]);
        }
#pragma unroll
        for (int i = 0; i < 4; ++i) {
            const int brow = wc * 64 + i * 16 + lrow;
            bfr[i] = *reinterpret_cast<const ix4*>(&Bbuf[buf][brow * 64 + koff]);
        }

        const int g = kt >> 1;
        float wsv[4];
#pragma unroll
        for (int ni = 0; ni < 4; ++ni)
            wsv[ni] = WS[g * T_BN + wc * 64 + ni * 16 + lrow];

#pragma unroll
        for (int mi = 0; mi < 4; ++mi) {
            ix4 s0 = __builtin_amdgcn_mfma_i32_16x16x64_i8(af[mi], bfr[0], (ix4){0,0,0,0}, 0, 0, 0);
            ix4 s1 = __builtin_amdgcn_mfma_i32_16x16x64_i8(af[mi], bfr[1], (ix4){0,0,0,0}, 0, 0, 0);
            ix4 s2 = __builtin_amdgcn_mfma_i32_16x16x64_i8(af[mi], bfr[2], (ix4){0,0,0,0}, 0, 0, 0);
            ix4 s3 = __builtin_amdgcn_mfma_i32_16x16x64_i8(af[mi], bfr[3], (ix4){0,0,0,0}, 0, 0, 0);
#pragma unroll
            for (int e = 0; e < 4; ++e) {
                facc[mi][0][e] += wsv[0] * (float)s0[e];
                facc[mi][1][e] += wsv[1] * (float)s1[e];
                facc[mi][2][e] += wsv[2] * (float)s2[e];
                facc[mi][3][e] += wsv[3] * (float)s3[e];
            }
        }

        if (more) writeA(&Abuf[buf ^ 1][0]);    // write-late: loads have landed
        __syncthreads();
    }

    // ---- epilogue: v = facc + bias (in_s folded); output fake-quant ----
    const float out_s = out_scale_p[0];
    const float out_inv = 1.0f / out_s;
    const float ozp = (float)out_zp_p[0];
    const int col = lane & 15;
    const int rgrp = lane >> 4;
#pragma unroll
    for (int ni = 0; ni < 4; ++ni) {
        const int n = n0 + wc * 64 + ni * 16 + col;
        const float bv = bias_f[n];
#pragma unroll
        for (int mi = 0; mi < 4; ++mi) {
#pragma unroll
            for (int j = 0; j < 4; ++j) {
                const int m = m0 + wr * 64 + mi * 16 + rgrp * 4 + j;
                float v = facc[mi][ni][j] + bv;
                float q = rintf(v * out_inv) + ozp;
                q = fminf(fmaxf(q, -128.0f), 127.0f);
                out[(size_t)m * N_DIM + n] = (q - ozp) * out_s;
            }
        }
    }
}

extern "C" void kernel_launch(void* const* d_in, const int* in_sizes, int n_in,
                              void* d_out, int out_size, void* d_ws, size_t ws_size,
                              hipStream_t stream) {
    const float* x          = (const float*)d_in[0];
    const int*   w_q        = (const int*)d_in[1];
    const float* w_scale    = (const float*)d_in[2];
    const int*   w_zp       = (const int*)d_in[3];
    const int*   bias_q     = (const int*)d_in[4];
    const float* bias_scale = (const float*)d_in[5];
    const float* in_scale   = (const float*)d_in[6];
    const int*   in_zp      = (const int*)d_in[7];
    const float* out_scale  = (const float*)d_in[8];
    const int*   out_zp     = (const int*)d_in[9];

    int8_t* Wd    = (int8_t*)d_ws;                                   // 1 MB
    float* bias_f = (float*)((char*)d_ws + (size_t)N_DIM * K_DIM);   // 4 KB

    prep_wd_kernel<<<N_DIM, 256, 0, stream>>>(w_q, w_zp, bias_q, bias_scale, Wd, bias_f);

    const int grid = (M_DIM / T_BM) * (N_DIM / T_BN);   // 512 * 8 = 4096
    gemm128_i8f_kernel<<<grid, 256, 0, stream>>>(x, Wd, w_scale, bias_f,
                                                 in_scale, in_zp, out_scale, out_zp,
                                                 (float*)d_out);
}

// Round 13
// 289.465 us; speedup vs baseline: 1.3807x; 1.3807x over previous
//
#include <hip/hip_runtime.h>
#include <hip/hip_bf16.h>
#include <stdint.h>

// Problem constants (B=8, S=8192, K=1024, N=1024, G=128)
#define M_DIM 65536
#define K_DIM 1024
#define N_DIM 1024
#define NGRP  8

// 128x128 i8 GEMM, BK=64 (r9 skeleton; A direct-from-global, B via LDS)
#define T_BM 128
#define T_BN 128
#define T_BK 64
#define T_NKT (K_DIM / T_BK)    // 16

#define PREP_WD_BLOCKS 1024
#define PREP_X8_BLOCKS ((M_DIM * (size_t)K_DIM) / (256 * 16))   // 16384

typedef float f32x4 __attribute__((ext_vector_type(4)));
typedef int   ix4   __attribute__((ext_vector_type(4)));

// ---------------- merged prep: wd (blocks 0..1023) + x8 quant (rest) ----------------
__global__ __launch_bounds__(256) void prep_all_kernel(
    const float* __restrict__ x,
    const int* __restrict__ w_q,
    const int* __restrict__ w_zp,
    const int* __restrict__ bias_q,
    const float* __restrict__ bias_scale,
    const float* __restrict__ in_scale_p, const int* __restrict__ in_zp_p,
    int8_t* __restrict__ Wd,
    float* __restrict__ bias_f,
    int8_t* __restrict__ Xq)
{
    const int t = threadIdx.x;
    if (blockIdx.x < PREP_WD_BLOCKS) {
        const int n = blockIdx.x;
        const int k0 = t * 4;
        const int g = k0 >> 7;
        const int zp = w_zp[n * NGRP + g];
        const int4 wq = *reinterpret_cast<const int4*>(w_q + (size_t)n * K_DIM + k0);
        union { int u; int8_t b[4]; } pk;
        pk.b[0] = (int8_t)(wq.x - zp);
        pk.b[1] = (int8_t)(wq.y - zp);
        pk.b[2] = (int8_t)(wq.z - zp);
        pk.b[3] = (int8_t)(wq.w - zp);
        *reinterpret_cast<int*>(Wd + (size_t)n * K_DIM + k0) = pk.u;
        if (t == 0) bias_f[n] = ((float)bias_q[n] - 128.0f) * bias_scale[n];
        return;
    }
    const float s = in_scale_p[0];
    const float inv = 1.0f / s;
    const float zp = (float)in_zp_p[0];
    const size_t i = ((size_t)(blockIdx.x - PREP_WD_BLOCKS) * 256 + t) * 16;
    float vv[16];
#pragma unroll
    for (int c = 0; c < 4; ++c) {
        const float4 v = *reinterpret_cast<const float4*>(x + i + c * 4);
        vv[c * 4 + 0] = v.x; vv[c * 4 + 1] = v.y;
        vv[c * 4 + 2] = v.z; vv[c * 4 + 3] = v.w;
    }
    union { int4 u; int8_t b[16]; } pk;
#pragma unroll
    for (int e = 0; e < 16; ++e) {
        float q = rintf(vv[e] * inv) + zp;       // RNE matches jnp.round
        q = fminf(fmaxf(q, -128.0f), 127.0f);
        pk.b[e] = (int8_t)(q - zp);
    }
    *reinterpret_cast<int4*>(Xq + i) = pk.u;
}

// ---------------- 128x128 i8 GEMM: r9 skeleton, A direct-from-global ----------------
// 256 thr = 4 waves (2x2), wave owns 64x64. B double-buffered in LDS (XOR
// swizzle, 0-conflict r2-r11); A-fragments loaded DIRECTLY from Xq8 into
// registers (16B/lane, 4 lanes per 64B line; 8KB/tile slice is L1-resident,
// panel L2-shared across the 8 nt-blocks per XCD). Register ping-pong
// afA/afB: A(kt+1) issued at top of phase kt -> consumed one full
// MFMA+CVT+barrier later (~700cyc latency cover). Per tile: stage B(kt+1)
// DMA | read B frags | 16 MFMA C=0 | CVT facc += ws*S | __syncthreads
// (drains B DMA + B ds_reads; A never touches LDS).
__global__ __launch_bounds__(256) void gemm128_i8d_kernel(
    const int8_t* __restrict__ Xq,
    const int8_t* __restrict__ Wd,
    const float* __restrict__ w_scale,
    const float* __restrict__ bias_f,
    const float* __restrict__ in_scale_p,
    const float* __restrict__ out_scale_p, const int* __restrict__ out_zp_p,
    float* __restrict__ out)
{
    __shared__ __align__(16) int8_t Bbuf[2][T_BN * T_BK];   // 2 x 8 KB
    __shared__ float WS[NGRP * T_BN];                        // 4 KB [g][n_local]

    const int t = threadIdx.x;
    // bijective XCD swizzle: grid=4096, 8 XCDs, 512 blocks/XCD;
    // consecutive local bids share the A (Xq) panel across nt=0..7.
    const int bid = (blockIdx.x & 7) * 512 + (blockIdx.x >> 3);
    const int nt = bid & 7;
    const int mt = bid >> 3;
    const int m0 = mt * T_BM;
    const int n0 = nt * T_BN;

    const int wid = t >> 6;
    const int lane = t & 63;
    const int wr = wid >> 1, wc = wid & 1;     // 2x2 waves, each owns 64x64
    const int lrow = lane & 15;
    const int kslot = lane >> 4;               // 16B k-chunk within 64B row
    const int koff = ((kslot ^ ((lrow >> 1) & 3)) << 4);   // B swizzle (r2-r11)
    const int widoff = wid * 1024;

    const int8_t* Abase = Xq + (size_t)m0 * K_DIM;
    const int8_t* Bbase = Wd + (size_t)n0 * K_DIM;

    // ---- preload w_scale panel [g][n_local], folded with in_s (r11-proven) ----
    {
        const float in_s = in_scale_p[0];
        const int nl = t >> 1;                 // 0..127
        const int g4 = (t & 1) * 4;
        const float4 wv = *reinterpret_cast<const float4*>(
            w_scale + (size_t)(n0 + nl) * NGRP + g4);
        WS[(g4 + 0) * T_BN + nl] = wv.x * in_s;
        WS[(g4 + 1) * T_BN + nl] = wv.y * in_s;
        WS[(g4 + 2) * T_BN + nl] = wv.z * in_s;
        WS[(g4 + 3) * T_BN + nl] = wv.w * in_s;
    }

    // B staging via global_load_lds, pre-swizzled source (0-conflict)
    auto stageB = [&](int8_t* dst, int kt) {
        const int k0 = kt * T_BK;
#pragma unroll
        for (int j = 0; j < 2; ++j) {
            const int c = j * 256 + t;
            const int r = c >> 2;
            const int sl = (c & 3) ^ ((r >> 1) & 3);
            const int8_t* src = Bbase + (size_t)r * K_DIM + k0 + sl * 16;
            __builtin_amdgcn_global_load_lds(
                (const __attribute__((address_space(1))) void*)src,
                (__attribute__((address_space(3))) void*)(dst + j * 4096 + widoff),
                16, 0, 0);
        }
    };

    // A-fragment direct load: lane's 16B at (row, kslot) of tile kt; no swizzle.
    const int8_t* Arow0 = Abase + (size_t)(wr * 64 + lrow) * K_DIM + kslot * 16;
#define LOAD_A(DST, KT)                                                       \
    _Pragma("unroll")                                                         \
    for (int i = 0; i < 4; ++i)                                               \
        DST[i] = *reinterpret_cast<const ix4*>(                               \
            Arow0 + (size_t)(i * 16) * K_DIM + (KT) * T_BK);

    f32x4 facc[4][4];
#pragma unroll
    for (int mi = 0; mi < 4; ++mi)
#pragma unroll
        for (int ni = 0; ni < 4; ++ni)
            facc[mi][ni] = (f32x4){0.f, 0.f, 0.f, 0.f};

    ix4 afA[4], afB[4];

    // prologue: A(0) to regs, B(0) to LDS buf0; barrier drains WS + B DMA
    LOAD_A(afA, 0);
    stageB(&Bbuf[0][0], 0);
    __syncthreads();

// one phase: prefetch A(next)+B(next), read B(cur), 16 MFMA, CVT, barrier
#define PHASE(AF_CUR, AF_NXT, CURBUF, KT)                                     \
    do {                                                                      \
        if ((KT) + 1 < T_NKT) {                                               \
            LOAD_A(AF_NXT, (KT) + 1);                                         \
            stageB(&Bbuf[(CURBUF) ^ 1][0], (KT) + 1);                         \
        }                                                                     \
        ix4 bfr[4];                                                           \
        _Pragma("unroll")                                                     \
        for (int i = 0; i < 4; ++i) {                                         \
            const int brow = wc * 64 + i * 16 + lrow;                         \
            bfr[i] = *reinterpret_cast<const ix4*>(                           \
                &Bbuf[CURBUF][brow * 64 + koff]);                             \
        }                                                                     \
        const int g = (KT) >> 1;                                              \
        float wsv[4];                                                         \
        _Pragma("unroll")                                                     \
        for (int ni = 0; ni < 4; ++ni)                                        \
            wsv[ni] = WS[g * T_BN + wc * 64 + ni * 16 + lrow];                \
        _Pragma("unroll")                                                     \
        for (int mi = 0; mi < 4; ++mi) {                                      \
            ix4 s0 = __builtin_amdgcn_mfma_i32_16x16x64_i8(AF_CUR[mi], bfr[0], (ix4){0,0,0,0}, 0, 0, 0); \
            ix4 s1 = __builtin_amdgcn_mfma_i32_16x16x64_i8(AF_CUR[mi], bfr[1], (ix4){0,0,0,0}, 0, 0, 0); \
            ix4 s2 = __builtin_amdgcn_mfma_i32_16x16x64_i8(AF_CUR[mi], bfr[2], (ix4){0,0,0,0}, 0, 0, 0); \
            ix4 s3 = __builtin_amdgcn_mfma_i32_16x16x64_i8(AF_CUR[mi], bfr[3], (ix4){0,0,0,0}, 0, 0, 0); \
            _Pragma("unroll")                                                 \
            for (int e = 0; e < 4; ++e) {                                     \
                facc[mi][0][e] += wsv[0] * (float)s0[e];                      \
                facc[mi][1][e] += wsv[1] * (float)s1[e];                      \
                facc[mi][2][e] += wsv[2] * (float)s2[e];                      \
                facc[mi][3][e] += wsv[3] * (float)s3[e];                      \
            }                                                                 \
        }                                                                     \
        __syncthreads();                                                      \
    } while (0)

#pragma unroll 1
    for (int kt2 = 0; kt2 < T_NKT; kt2 += 2) {
        PHASE(afA, afB, 0, kt2);          // even tile: buf0, frags afA
        PHASE(afB, afA, 1, kt2 + 1);      // odd tile:  buf1, frags afB
    }

#undef PHASE
#undef LOAD_A

    // ---- epilogue: v = facc + bias (in_s folded); output fake-quant ----
    const float out_s = out_scale_p[0];
    const float out_inv = 1.0f / out_s;
    const float ozp = (float)out_zp_p[0];
    const int col = lane & 15;
    const int rgrp = lane >> 4;
#pragma unroll
    for (int ni = 0; ni < 4; ++ni) {
        const int n = n0 + wc * 64 + ni * 16 + col;
        const float bv = bias_f[n];
#pragma unroll
        for (int mi = 0; mi < 4; ++mi) {
#pragma unroll
            for (int j = 0; j < 4; ++j) {
                const int m = m0 + wr * 64 + mi * 16 + rgrp * 4 + j;
                float v = facc[mi][ni][j] + bv;
                float q = rintf(v * out_inv) + ozp;
                q = fminf(fmaxf(q, -128.0f), 127.0f);
                out[(size_t)m * N_DIM + n] = (q - ozp) * out_s;
            }
        }
    }
}

extern "C" void kernel_launch(void* const* d_in, const int* in_sizes, int n_in,
                              void* d_out, int out_size, void* d_ws, size_t ws_size,
                              hipStream_t stream) {
    const float* x          = (const float*)d_in[0];
    const int*   w_q        = (const int*)d_in[1];
    const float* w_scale    = (const float*)d_in[2];
    const int*   w_zp       = (const int*)d_in[3];
    const int*   bias_q     = (const int*)d_in[4];
    const float* bias_scale = (const float*)d_in[5];
    const float* in_scale   = (const float*)d_in[6];
    const int*   in_zp      = (const int*)d_in[7];
    const float* out_scale  = (const float*)d_in[8];
    const int*   out_zp     = (const int*)d_in[9];

    const size_t xq8_bytes = (size_t)M_DIM * K_DIM;          // 67.1 MB
    const size_t wd_bytes  = (size_t)N_DIM * K_DIM;          // 1 MB

    int8_t* Xq8   = (int8_t*)d_ws;
    int8_t* Wd    = (int8_t*)((char*)d_ws + xq8_bytes);
    float* bias_f = (float*)((char*)d_ws + xq8_bytes + wd_bytes);

    prep_all_kernel<<<(int)(PREP_WD_BLOCKS + PREP_X8_BLOCKS), 256, 0, stream>>>(
        x, w_q, w_zp, bias_q, bias_scale, in_scale, in_zp, Wd, bias_f, Xq8);

    const int grid = (M_DIM / T_BM) * (N_DIM / T_BN);   // 512 * 8 = 4096
    gemm128_i8d_kernel<<<grid, 256, 0, stream>>>(Xq8, Wd, w_scale, bias_f,
                                                 in_scale, out_scale, out_zp,
                                                 (float*)d_out);
}

// Round 14
// 221.675 us; speedup vs baseline: 1.8030x; 1.3058x over previous
//
#include <hip/hip_runtime.h>
#include <hip/hip_bf16.h>
#include <stdint.h>

// Problem constants (B=8, S=8192, K=1024, N=1024, G=128)
#define M_DIM 65536
#define K_DIM 1024
#define N_DIM 1024
#define NGRP  8

// 128x128 i8 GEMM, BK=64, static dbuf (r9 verbatim — proven 154us)
#define T_BM 128
#define T_BN 128
#define T_BK 64
#define T_NKT (K_DIM / T_BK)    // 16

#define PREP_WD_BLOCKS 1024
#define PREP_X8_BLOCKS ((M_DIM * (size_t)K_DIM) / (256 * 16))   // 16384

typedef float f32x4 __attribute__((ext_vector_type(4)));
typedef int   ix4   __attribute__((ext_vector_type(4)));

// ---------------- merged prep: wd (blocks 0..1023) + x8 quant (rest) ----------------
// Outputs byte-identical to the split r9 prep kernels (verified r13).
__global__ __launch_bounds__(256) void prep_all_kernel(
    const float* __restrict__ x,
    const int* __restrict__ w_q,
    const int* __restrict__ w_zp,
    const int* __restrict__ bias_q,
    const float* __restrict__ bias_scale,
    const float* __restrict__ in_scale_p, const int* __restrict__ in_zp_p,
    int8_t* __restrict__ Wd,
    float* __restrict__ bias_f,
    int8_t* __restrict__ Xq)
{
    const int t = threadIdx.x;
    if (blockIdx.x < PREP_WD_BLOCKS) {
        const int n = blockIdx.x;
        const int k0 = t * 4;
        const int g = k0 >> 7;
        const int zp = w_zp[n * NGRP + g];
        const int4 wq = *reinterpret_cast<const int4*>(w_q + (size_t)n * K_DIM + k0);
        union { int u; int8_t b[4]; } pk;
        pk.b[0] = (int8_t)(wq.x - zp);
        pk.b[1] = (int8_t)(wq.y - zp);
        pk.b[2] = (int8_t)(wq.z - zp);
        pk.b[3] = (int8_t)(wq.w - zp);
        *reinterpret_cast<int*>(Wd + (size_t)n * K_DIM + k0) = pk.u;
        if (t == 0) bias_f[n] = ((float)bias_q[n] - 128.0f) * bias_scale[n];
        return;
    }
    const float s = in_scale_p[0];
    const float inv = 1.0f / s;
    const float zp = (float)in_zp_p[0];
    const size_t i = ((size_t)(blockIdx.x - PREP_WD_BLOCKS) * 256 + t) * 16;
    float vv[16];
#pragma unroll
    for (int c = 0; c < 4; ++c) {
        const float4 v = *reinterpret_cast<const float4*>(x + i + c * 4);
        vv[c * 4 + 0] = v.x; vv[c * 4 + 1] = v.y;
        vv[c * 4 + 2] = v.z; vv[c * 4 + 3] = v.w;
    }
    union { int4 u; int8_t b[16]; } pk;
#pragma unroll
    for (int e = 0; e < 16; ++e) {
        float q = rintf(vv[e] * inv) + zp;       // RNE matches jnp.round
        q = fminf(fmaxf(q, -128.0f), 127.0f);
        pk.b[e] = (int8_t)(q - zp);
    }
    *reinterpret_cast<int4*>(Xq + i) = pk.u;
}

// ---------------- 128x128 i8 GEMM (round-9 kernel, verbatim) ----------------
// 256 thr = 4 waves (2x2), wave owns 64x64. Static dbuf, plain __syncthreads.
// Per K-64 tile: stage next buf (4 gload_lds/thread), read frags (8 b128),
// 16 MFMA i8 -> i32 (C=0, independent), exact per-tile group combine
// facc += ws_g * S_t, one __syncthreads (drains vmcnt+lgkm; WAR/RAW covered).
// Measured r9: gemm 154us, absmax 0.15625. All structural variants
// (ring+vmcnt r10, group-pair acc r11, fused quant r12, direct-A r13) lost.
__global__ __launch_bounds__(256, 3) void gemm128_i8_kernel(
    const int8_t* __restrict__ Xq,
    const int8_t* __restrict__ Wd,
    const float* __restrict__ w_scale,
    const float* __restrict__ bias_f,
    const float* __restrict__ in_scale_p,
    const float* __restrict__ out_scale_p, const int* __restrict__ out_zp_p,
    float* __restrict__ out)
{
    __shared__ __align__(16) int8_t Abuf[2][T_BM * T_BK];   // 2 x 8 KB
    __shared__ __align__(16) int8_t Bbuf[2][T_BN * T_BK];   // 2 x 8 KB
    __shared__ float WS[NGRP * T_BN];                        // 4 KB [g][n_local]

    const int t = threadIdx.x;
    // bijective XCD swizzle: grid=4096, 8 XCDs, 512 blocks/XCD;
    // consecutive local bids share the A panel (mt) across nt=0..7.
    const int bid = (blockIdx.x & 7) * 512 + (blockIdx.x >> 3);
    const int nt = bid & 7;
    const int mt = bid >> 3;
    const int m0 = mt * T_BM;
    const int n0 = nt * T_BN;

    const int wid = t >> 6;
    const int lane = t & 63;
    const int wr = wid >> 1, wc = wid & 1;     // 2x2 waves, each owns 64x64
    const int lrow = lane & 15;
    const int kslot = lane >> 4;               // 16B k-chunk within 64B row
    const int koff = ((kslot ^ ((lrow >> 1) & 3)) << 4);   // XOR swizzle (r2-r13)
    const int widoff = wid * 1024;

    const int8_t* Abase = Xq + (size_t)m0 * K_DIM;
    const int8_t* Bbase = Wd + (size_t)n0 * K_DIM;

    // ---- preload w_scale panel [g][n_local] (drained by prologue barrier) ----
    {
        const int nl = t >> 1;                 // 0..127
        const int g4 = (t & 1) * 4;
        const float4 wv = *reinterpret_cast<const float4*>(
            w_scale + (size_t)(n0 + nl) * NGRP + g4);
        WS[(g4 + 0) * T_BN + nl] = wv.x;
        WS[(g4 + 1) * T_BN + nl] = wv.y;
        WS[(g4 + 2) * T_BN + nl] = wv.z;
        WS[(g4 + 3) * T_BN + nl] = wv.w;
    }

    // stage one 128x64B tile (512 chunks, 2/thread), pre-swizzled source
    auto stage = [&](int8_t* dst, const int8_t* panel, int kt) {
        const int k0 = kt * T_BK;
#pragma unroll
        for (int j = 0; j < 2; ++j) {
            const int c = j * 256 + t;                 // 16B chunk id 0..511
            const int r = c >> 2;                      // row 0..127
            const int sl = (c & 3) ^ ((r >> 1) & 3);   // logical k-slot at phys slot
            const int8_t* src = panel + (size_t)r * K_DIM + k0 + sl * 16;
            __builtin_amdgcn_global_load_lds(
                (const __attribute__((address_space(1))) void*)src,
                (__attribute__((address_space(3))) void*)(dst + j * 4096 + widoff),
                16, 0, 0);
        }
    };

    f32x4 facc[4][4];
#pragma unroll
    for (int mi = 0; mi < 4; ++mi)
#pragma unroll
        for (int ni = 0; ni < 4; ++ni)
            facc[mi][ni] = (f32x4){0.f, 0.f, 0.f, 0.f};

    // prologue: stage tile 0 into buf 0 (WS + DMA drained by syncthreads)
    stage(&Abuf[0][0], Abase, 0);
    stage(&Bbuf[0][0], Bbase, 0);
    __syncthreads();

    int buf = 0;
#pragma unroll 1
    for (int kt = 0; kt < T_NKT; ++kt) {
        if (kt + 1 < T_NKT) {
            stage(&Abuf[buf ^ 1][0], Abase, kt + 1);
            stage(&Bbuf[buf ^ 1][0], Bbase, kt + 1);
        }

        ix4 af[4], bfr[4];
#pragma unroll
        for (int i = 0; i < 4; ++i) {
            const int arow = wr * 64 + i * 16 + lrow;
            af[i] = *reinterpret_cast<const ix4*>(&Abuf[buf][arow * 64 + koff]);
        }
#pragma unroll
        for (int i = 0; i < 4; ++i) {
            const int brow = wc * 64 + i * 16 + lrow;
            bfr[i] = *reinterpret_cast<const ix4*>(&Bbuf[buf][brow * 64 + koff]);
        }

        const int g = kt >> 1;
        float wsv[4];
#pragma unroll
        for (int ni = 0; ni < 4; ++ni)
            wsv[ni] = WS[g * T_BN + wc * 64 + ni * 16 + lrow];

#pragma unroll
        for (int mi = 0; mi < 4; ++mi) {
            ix4 s0 = __builtin_amdgcn_mfma_i32_16x16x64_i8(af[mi], bfr[0], (ix4){0,0,0,0}, 0, 0, 0);
            ix4 s1 = __builtin_amdgcn_mfma_i32_16x16x64_i8(af[mi], bfr[1], (ix4){0,0,0,0}, 0, 0, 0);
            ix4 s2 = __builtin_amdgcn_mfma_i32_16x16x64_i8(af[mi], bfr[2], (ix4){0,0,0,0}, 0, 0, 0);
            ix4 s3 = __builtin_amdgcn_mfma_i32_16x16x64_i8(af[mi], bfr[3], (ix4){0,0,0,0}, 0, 0, 0);
#pragma unroll
            for (int e = 0; e < 4; ++e) {
                facc[mi][0][e] += wsv[0] * (float)s0[e];
                facc[mi][1][e] += wsv[1] * (float)s1[e];
                facc[mi][2][e] += wsv[2] * (float)s2[e];
                facc[mi][3][e] += wsv[3] * (float)s3[e];
            }
        }

        __syncthreads();
        buf ^= 1;
    }

    // ---- epilogue: v = in_s * facc + bias; output fake-quant ----
    const float in_s  = in_scale_p[0];
    const float out_s = out_scale_p[0];
    const float out_inv = 1.0f / out_s;
    const float ozp = (float)out_zp_p[0];
    const int col = lane & 15;
    const int rgrp = lane >> 4;
#pragma unroll
    for (int ni = 0; ni < 4; ++ni) {
        const int n = n0 + wc * 64 + ni * 16 + col;
        const float bv = bias_f[n];
#pragma unroll
        for (int mi = 0; mi < 4; ++mi) {
#pragma unroll
            for (int j = 0; j < 4; ++j) {
                const int m = m0 + wr * 64 + mi * 16 + rgrp * 4 + j;
                float v = in_s * facc[mi][ni][j] + bv;
                float q = rintf(v * out_inv) + ozp;
                q = fminf(fmaxf(q, -128.0f), 127.0f);
                out[(size_t)m * N_DIM + n] = (q - ozp) * out_s;
            }
        }
    }
}

extern "C" void kernel_launch(void* const* d_in, const int* in_sizes, int n_in,
                              void* d_out, int out_size, void* d_ws, size_t ws_size,
                              hipStream_t stream) {
    const float* x          = (const float*)d_in[0];
    const int*   w_q        = (const int*)d_in[1];
    const float* w_scale    = (const float*)d_in[2];
    const int*   w_zp       = (const int*)d_in[3];
    const int*   bias_q     = (const int*)d_in[4];
    const float* bias_scale = (const float*)d_in[5];
    const float* in_scale   = (const float*)d_in[6];
    const int*   in_zp      = (const int*)d_in[7];
    const float* out_scale  = (const float*)d_in[8];
    const int*   out_zp     = (const int*)d_in[9];

    const size_t xq8_bytes = (size_t)M_DIM * K_DIM;          // 67.1 MB
    const size_t wd_bytes  = (size_t)N_DIM * K_DIM;          // 1 MB

    int8_t* Xq8   = (int8_t*)d_ws;
    int8_t* Wd    = (int8_t*)((char*)d_ws + xq8_bytes);
    float* bias_f = (float*)((char*)d_ws + xq8_bytes + wd_bytes);

    prep_all_kernel<<<(int)(PREP_WD_BLOCKS + PREP_X8_BLOCKS), 256, 0, stream>>>(
        x, w_q, w_zp, bias_q, bias_scale, in_scale, in_zp, Wd, bias_f, Xq8);

    const int grid = (M_DIM / T_BM) * (N_DIM / T_BN);   // 512 * 8 = 4096
    gemm128_i8_kernel<<<grid, 256, 0, stream>>>(Xq8, Wd, w_scale, bias_f,
                                                in_scale, out_scale, out_zp,
                                                (float*)d_out);
}